// Round 2
// baseline (102.188 us; speedup 1.0000x reference)
//
#include <hip/hip_runtime.h>

typedef _Float16 half8 __attribute__((ext_vector_type(8)));
typedef float floatx4 __attribute__((ext_vector_type(4)));
typedef float floatx2 __attribute__((ext_vector_type(2)));
typedef unsigned int uintx2 __attribute__((ext_vector_type(2)));

#define BB 8
#define NN 64
#define DD 64
#define EE 32

__device__ __forceinline__ float sigmoidf_(float x) { return 1.f / (1.f + __expf(-x)); }
__device__ __forceinline__ float tanhf_(float x) {
    float e = __expf(2.f * x);
    return (e - 1.f) / (e + 1.f);
}
__device__ __forceinline__ floatx2 relu2(floatx2 v) {
    floatx2 z = {0.f, 0.f};
    return __builtin_elementwise_max(v, z);
}

// ---------------- single fused kernel, ZERO workspace ----------------
// One block per (b, inode-pair): 256 blocks x 512 threads (8 waves).
// Wave w: jw = w&3 (d_j block), i-half = w>>2 (32 i's). Per i-iteration:
//   A-fragment (W rows) converted fp32->fp16 IN-REGISTER from W_e (L2-resident),
//   8 MFMAs (two inodes x 4 e-blocks) share it -> halves per-block W traffic.
// Fold partials with permlane32_swap + permlane16_swap (VALU pipe, not DS):
// one quarter-wave LDS write per inode per iter. Tail: P-reduce || GRU1,
// then GRU2, all in-block. No prep kernel, no d_ws reads or writes.
__global__ __launch_bounds__(512, 2)
void fused_kernel(const float* __restrict__ W_e,
                  const float* __restrict__ edges,
                  const float* __restrict__ nodes,
                  const float* __restrict__ mask,
                  const float* __restrict__ b_e,
                  const float* __restrict__ K,
                  const float* __restrict__ R,
                  const float* __restrict__ bias,
                  float* __restrict__ out) {
    const int b      = blockIdx.x >> 5;     // 8 batches
    const int pairi  = blockIdx.x & 31;     // 32 inode pairs
    const int inode0 = pairi * 2;
    const int tid    = threadIdx.x;
    const int w      = tid >> 6;            // 0..7
    const int jw     = w & 3;               // jj (d_j) block
    const int ibase  = (w >> 2) * 32;       // d_i half
    const int lane   = tid & 63;
    const int quad   = lane >> 4;
    const int col    = lane & 15;

    __shared__ float S[2][4][16][65];       // [g][jw][colpart][i]; pad 65 -> conflict-free (33.3 KB)
    __shared__ float P[2][4][64];
    __shared__ float aggs[2][64], h1s[2][64], ns[2][64];
    __shared__ float gx[2][192], g1[2][192], g2[2][192];

    if (tid < 128) {                        // own x-rows for GRU step 1
        int g = tid >> 6, d = tid & 63;
        ns[g][d] = nodes[(b * 64 + inode0 + g) * 64 + d];
    }

    // B-operand fragments: e_lin = inode0*64 + eb*16 + col (contiguous 128 e's), k = quad*8+j
    half8 ef[8];
    const float* ebase = edges + (size_t)(b * 4096 + inode0 * 64) * 32;
#pragma unroll
    for (int eb = 0; eb < 8; ++eb) {
        const float* ep = ebase + (eb * 16 + col) * 32 + quad * 8;
        floatx4 e0 = *reinterpret_cast<const floatx4*>(ep);
        floatx4 e1 = *reinterpret_cast<const floatx4*>(ep + 4);
#pragma unroll
        for (int j = 0; j < 4; ++j) {
            ef[eb][j]     = (_Float16)e0[j];
            ef[eb][4 + j] = (_Float16)e1[j];
        }
    }

    // epilogue multipliers: xm[eb] = mask[e] * nodes[j(e)][jj-rows]; nodes part shared by the 2 inodes
    floatx2 nd[4][2];
#pragma unroll
    for (int q4 = 0; q4 < 4; ++q4) {
        int j = q4 * 16 + col;
#pragma unroll
        for (int rp = 0; rp < 2; ++rp) {
            int jj = jw * 16 + quad * 4 + rp * 2;
            nd[q4][rp][0] = nodes[(b * 64 + j) * 64 + jj];
            nd[q4][rp][1] = nodes[(b * 64 + j) * 64 + jj + 1];
        }
    }
    floatx2 xm[8][2];
#pragma unroll
    for (int eb = 0; eb < 8; ++eb) {
        float mk = mask[b * 4096 + inode0 * 64 + eb * 16 + col];
        xm[eb][0] = nd[eb & 3][0] * mk;
        xm[eb][1] = nd[eb & 3][1] * mk;
    }

    // A-operand on the fly: af[j] = (fp16) W_e[(quad*8+j)*4096 + i*64 + jw*16 + col]
    const float* wb   = W_e + (size_t)(quad * 8) * 4096 + jw * 16 + col;
    const float* bptr = b_e + jw * 16 + quad * 4;

    float fA[8];
    auto LDW = [&](int i) {
#pragma unroll
        for (int j = 0; j < 8; ++j) fA[j] = wb[(size_t)j * 4096 + i * 64];
    };
    auto CVT = [&]() {
        half8 a;
#pragma unroll
        for (int j = 0; j < 8; ++j) a[j] = (_Float16)fA[j];
        return a;
    };

    LDW(ibase);
    floatx4 bf0 = *reinterpret_cast<const floatx4*>(bptr + ibase * 64);
    floatx4 bf1 = *reinterpret_cast<const floatx4*>(bptr + (ibase + 1) * 64);
    half8 af0 = CVT();
    LDW(ibase + 1);
    half8 af1 = CVT();

    for (int ii = 0; ii < 32; ++ii) {
        int ip2 = ibase + ((ii + 2) & 31);      // wrap prefetch (harmless reload at end)
        LDW(ip2);                               // issue early; converted after MFMAs
        floatx4 bfn = *reinterpret_cast<const floatx4*>(bptr + ip2 * 64);

        floatx4 c[8];
#pragma unroll
        for (int eb = 0; eb < 8; ++eb)
            c[eb] = __builtin_amdgcn_mfma_f32_16x16x32_f16(af0, ef[eb], bf0, 0, 0, 0);

#pragma unroll
        for (int g = 0; g < 2; ++g) {
            floatx2 sv = {0.f, 0.f};
#pragma unroll
            for (int e4 = 0; e4 < 4; ++e4) {
                int eb = g * 4 + e4;
                floatx2* cp = reinterpret_cast<floatx2*>(&c[eb]);
                sv += relu2(cp[0]) * xm[eb][0];
                sv += relu2(cp[1]) * xm[eb][1];
            }
            float s = sv[0] + sv[1];
            // quad folds on the VALU pipe; summed-pair trick is exchange-convention-proof
            uintx2 p32 = __builtin_amdgcn_permlane32_swap(__float_as_uint(s), __float_as_uint(s),
                                                          false, false);
            s = __uint_as_float(p32[0]) + __uint_as_float(p32[1]);
#if __has_builtin(__builtin_amdgcn_permlane16_swap)
            uintx2 p16 = __builtin_amdgcn_permlane16_swap(__float_as_uint(s), __float_as_uint(s),
                                                          false, false);
            s = __uint_as_float(p16[0]) + __uint_as_float(p16[1]);
#else
            s += __shfl_xor(s, 16);
#endif
            if (lane < 16) S[g][jw][lane][ibase + ii] = s;   // banks (lane+i)%32: conflict-free
        }

        half8 afn = CVT();                      // vmcnt wait lands here, after MFMA issue
        af0 = af1; bf0 = bf1; af1 = afn; bf1 = bfn;
    }
    __syncthreads();

    // phase 1: P-reduction, all 512 threads (one (g,ww) pair per wave)
    {
        int g = tid >> 8, ww = (tid >> 6) & 3, ii = tid & 63;
        float p = 0.f;
#pragma unroll
        for (int l = 0; l < 16; ++l) p += S[g][ww][l][ii];
        P[g][ww][ii] = p;
    }
    __syncthreads();

    // phase 2: agg rows (128)  ||  GRU1 x@K for both own rows (384)
    if (tid < 128) {
        int g = tid >> 6, d = tid & 63;
        aggs[g][d] = P[g][0][d] + P[g][1][d] + P[g][2][d] + P[g][3][d];
    } else {
        int u = tid - 128;
        int g = (u >= 192) ? 1 : 0;
        int t = u - g * 192;
        float a = bias[t];
#pragma unroll 8
        for (int k = 0; k < 64; ++k) a = fmaf(ns[g][k], K[k * 192 + t], a);
        gx[g][t] = a;
    }
    __syncthreads();

    // phase 3: finish GRU1 (128)  ||  GRU2 g1 = agg@K (384)
    if (tid < 128) {
        int g = tid >> 6, d = tid & 63;
        float z  = sigmoidf_(gx[g][d]        + bias[192 + d]);
        float r  = sigmoidf_(gx[g][64 + d]   + bias[256 + d]);
        float hh = tanhf_   (gx[g][128 + d]  + r * bias[320 + d]);
        h1s[g][d] = (1.f - z) * hh;             // h_prev = 0
    } else {
        int u = tid - 128;
        int g = (u >= 192) ? 1 : 0;
        int t = u - g * 192;
        float a = bias[t];
#pragma unroll 8
        for (int k = 0; k < 64; ++k) a = fmaf(aggs[g][k], K[k * 192 + t], a);
        g1[g][t] = a;
    }
    __syncthreads();

    // phase 4: GRU2 g2 = h1@R (384 threads, two rows in parallel)
    if (tid < 384) {
        int g = (tid >= 192) ? 1 : 0;
        int t = tid - g * 192;
        float a = bias[192 + t];
#pragma unroll 8
        for (int k = 0; k < 64; ++k) a = fmaf(h1s[g][k], R[k * 192 + t], a);
        g2[g][t] = a;
    }
    __syncthreads();

    if (tid < 128) {
        int g = tid >> 6, d = tid & 63;
        float z  = sigmoidf_(g1[g][d]       + g2[g][d]);
        float r  = sigmoidf_(g1[g][64 + d]  + g2[g][64 + d]);
        float hh = tanhf_   (g1[g][128 + d] + r * g2[g][128 + d]);
        out[(b * 64 + inode0 + g) * 64 + d] = z * h1s[g][d] + (1.f - z) * hh;
    }
}

extern "C" void kernel_launch(void* const* d_in, const int* in_sizes, int n_in,
                              void* d_out, int out_size, void* d_ws, size_t ws_size,
                              hipStream_t stream) {
    const float* nodes = (const float*)d_in[0];
    const float* edges = (const float*)d_in[1];
    const float* mask  = (const float*)d_in[2];
    const float* W_e   = (const float*)d_in[3];
    const float* b_e   = (const float*)d_in[4];
    const float* gk    = (const float*)d_in[5];
    const float* gr    = (const float*)d_in[6];
    const float* gb    = (const float*)d_in[7];
    float* out = (float*)d_out;

    (void)d_ws; (void)ws_size;   // workspace intentionally untouched

    fused_kernel<<<256, 512, 0, stream>>>(W_e, edges, nodes, mask, b_e, gk, gr, gb, out);
}

// Round 3
// 94.781 us; speedup vs baseline: 1.0782x; 1.0782x over previous
//
#include <hip/hip_runtime.h>

typedef _Float16 half8 __attribute__((ext_vector_type(8)));
typedef float floatx4 __attribute__((ext_vector_type(4)));
typedef float floatx2 __attribute__((ext_vector_type(2)));
typedef unsigned int uintx2 __attribute__((ext_vector_type(2)));

#define BB 8
#define NN 64
#define DD 64
#define EE 32

__device__ __forceinline__ float sigmoidf_(float x) { return 1.f / (1.f + __expf(-x)); }
__device__ __forceinline__ float tanhf_(float x) {
    float e = __expf(2.f * x);
    return (e - 1.f) / (e + 1.f);
}
__device__ __forceinline__ floatx2 relu2(floatx2 v) {
    floatx2 z = {0.f, 0.f};
    return __builtin_elementwise_max(v, z);
}

// ---------------- prep: W transpose -> fp16 only ----------------
// 64 blocks x 256 threads: WT[d][k] = (fp16)W_e[k][d]   (4096 x 32, A-operand friendly)
__global__ void prep_kernel(const float* __restrict__ W_e, _Float16* __restrict__ WT) {
    const int tid = threadIdx.x;
    const int d   = blockIdx.x * 64 + (tid & 63);
    const int kq  = tid >> 6;                     // k = kq*8 + j
    half8 buf;
#pragma unroll
    for (int j = 0; j < 8; ++j)
        buf[j] = (_Float16)W_e[(kq * 8 + j) * 4096 + d];   // coalesced across d
    *reinterpret_cast<half8*>(WT + d * 32 + kq * 8) = buf;
}

// ---------------- fused: A-GEMM + relu + message + mask + j-sum + GRU1 + GRU2 ----------------
// One block per (b, i_node); 512 blocks x 512 threads (8 waves), 2 blocks/CU resident.
// Round-1 structure (94.9 us) restored: WT fp16 loads keep live VGPRs ~90 < 128
// (round-2 lesson: on-the-fly W_e conversion starved registers -> compiler sank
// the ef/xm loads into the loop -> 3000 cyc/iter latency chains).
// Main loop: permlane32_swap + permlane16_swap folds (VALU pipe), one 16-lane
// LDS write per iter into conflict-free S[jw][lane][i] (stride 65).
__global__ __launch_bounds__(512, 4)
void fused_kernel(const _Float16* __restrict__ WT,
                  const float* __restrict__ edges,
                  const float* __restrict__ nodes,
                  const float* __restrict__ mask,
                  const float* __restrict__ b_e,
                  const float* __restrict__ K,
                  const float* __restrict__ R,
                  const float* __restrict__ bias,
                  float* __restrict__ out) {
    const int b     = blockIdx.x >> 6;
    const int inode = blockIdx.x & 63;
    const int tid   = threadIdx.x;
    const int w     = tid >> 6;          // 0..7
    const int jw    = w & 3;             // jj-block
    const int ibase = (w >> 2) * 32;     // i-half
    const int lane  = tid & 63;
    const int quad  = lane >> 4;
    const int col   = lane & 15;
    const int row   = b * 64 + inode;

    __shared__ float S[4][16][65];       // [jw][colpart][i]; pad 65 -> conflict-free (16.6 KB)
    __shared__ float P[4][64];
    __shared__ float aggs[64], h1s[64], ns[64];
    __shared__ float gx[192], g1[192], g2[192];

    if (tid < 64) ns[tid] = nodes[row * 64 + tid];   // this block's own x-row (GRU1 input)

    // B-operand fragments from fp32 edges, converted in-register (loop-invariant)
    half8 ef[4];
#pragma unroll
    for (int eb = 0; eb < 4; ++eb) {
        const float* ep = edges + (b * 4096 + inode * 64 + eb * 16 + col) * 32 + quad * 8;
        floatx4 e0 = *reinterpret_cast<const floatx4*>(ep);
        floatx4 e1 = *reinterpret_cast<const floatx4*>(ep + 4);
#pragma unroll
        for (int j = 0; j < 4; ++j) {
            ef[eb][j]     = (_Float16)e0[j];
            ef[eb][4 + j] = (_Float16)e1[j];
        }
    }

    // epilogue multipliers: xm[eb][rp] = {mask*nodes for r=2rp, 2rp+1}
    floatx2 xm[4][2];
#pragma unroll
    for (int eb = 0; eb < 4; ++eb) {
        int j = eb * 16 + col;
        float mk = mask[b * 4096 + inode * 64 + j];
#pragma unroll
        for (int r = 0; r < 4; ++r) {
            int jj = jw * 16 + quad * 4 + r;
            xm[eb][r >> 1][r & 1] = mk * nodes[(b * 64 + j) * 64 + jj];
        }
    }

    // A-operand: WT rows d = i*64 + jw*16 + col, k = quad*8 + j
    const _Float16* aptr = WT + (jw * 16 + col) * 32 + quad * 8;
    const float*    bptr = b_e + jw * 16 + quad * 4;

    // depth-2 software pipeline over this wave's 32 i's
    half8   af0 = *reinterpret_cast<const half8*>(aptr + ibase * 2048);
    floatx4 bf0 = *reinterpret_cast<const floatx4*>(bptr + ibase * 64);
    half8   af1 = *reinterpret_cast<const half8*>(aptr + (ibase + 1) * 2048);
    floatx4 bf1 = *reinterpret_cast<const floatx4*>(bptr + (ibase + 1) * 64);

    for (int ii = 0; ii < 32; ++ii) {
        int ip2 = ibase + ((ii + 2) & 31);   // wrap prefetch (harmless reload at end)
        half8   afn = *reinterpret_cast<const half8*>(aptr + ip2 * 2048);
        floatx4 bfn = *reinterpret_cast<const floatx4*>(bptr + ip2 * 64);

        floatx4 c[4];
        c[0] = __builtin_amdgcn_mfma_f32_16x16x32_f16(af0, ef[0], bf0, 0, 0, 0);
        c[1] = __builtin_amdgcn_mfma_f32_16x16x32_f16(af0, ef[1], bf0, 0, 0, 0);
        c[2] = __builtin_amdgcn_mfma_f32_16x16x32_f16(af0, ef[2], bf0, 0, 0, 0);
        c[3] = __builtin_amdgcn_mfma_f32_16x16x32_f16(af0, ef[3], bf0, 0, 0, 0);

        floatx2 sv = {0.f, 0.f};
#pragma unroll
        for (int eb = 0; eb < 4; ++eb) {
            floatx2* cp = reinterpret_cast<floatx2*>(&c[eb]);
            sv += relu2(cp[0]) * xm[eb][0];
            sv += relu2(cp[1]) * xm[eb][1];
        }
        float s = sv[0] + sv[1];

        // quad folds on the VALU pipe (not DS); summed-pair trick is
        // exchange-convention-proof: s_new[l] = s[l] + s[partner(l)].
        uintx2 p32 = __builtin_amdgcn_permlane32_swap(__float_as_uint(s), __float_as_uint(s),
                                                      false, false);
        s = __uint_as_float(p32[0]) + __uint_as_float(p32[1]);
#if __has_builtin(__builtin_amdgcn_permlane16_swap)
        uintx2 p16 = __builtin_amdgcn_permlane16_swap(__float_as_uint(s), __float_as_uint(s),
                                                      false, false);
        s = __uint_as_float(p16[0]) + __uint_as_float(p16[1]);
#else
        s += __shfl_xor(s, 16);
#endif
        if (lane < 16) S[jw][lane][ibase + ii] = s;   // banks (lane+i)%32: conflict-free

        af0 = af1; bf0 = bf1; af1 = afn; bf1 = bfn;
    }
    __syncthreads();

    // phase 1: P-reduction (waves 0-3)  ||  GRU1 x@K part for own row (waves 4-6)
    if (tid < 256) {
        int ii = tid & 63, ww = tid >> 6;
        float p = 0.f;
#pragma unroll
        for (int l = 0; l < 16; ++l) p += S[ww][l][ii];   // stride-1 across lanes: conflict-free
        P[ww][ii] = p;
    } else if (tid < 448) {
        int t = tid - 256;
        float a = bias[t];
#pragma unroll 8
        for (int k = 0; k < 64; ++k) a = fmaf(ns[k], K[k * 192 + t], a);
        gx[t] = a;
    }
    __syncthreads();

    // phase 2: agg row  ||  finish GRU1 (h=0 => h1 = (1-z)*tanh(xh + r*b1h))
    if (tid < 64) {
        aggs[tid] = P[0][tid] + P[1][tid] + P[2][tid] + P[3][tid];
    } else if (tid < 128) {
        int d = tid - 64;
        float z  = sigmoidf_(gx[d]       + bias[192 + d]);
        float r  = sigmoidf_(gx[64 + d]  + bias[256 + d]);
        float hh = tanhf_   (gx[128 + d] + r * bias[320 + d]);
        h1s[d] = (1.f - z) * hh;
    }
    __syncthreads();

    // phase 3: GRU step 2 matmuls in parallel (g1 = agg@K on 0-191, g2 = h1@R on 192-383)
    if (tid < 192) {
        float a1 = bias[tid];
#pragma unroll 8
        for (int k = 0; k < 64; ++k) a1 = fmaf(aggs[k], K[k * 192 + tid], a1);
        g1[tid] = a1;
    } else if (tid < 384) {
        int t = tid - 192;
        float a2 = bias[192 + t];
#pragma unroll 8
        for (int k = 0; k < 64; ++k) a2 = fmaf(h1s[k], R[k * 192 + t], a2);
        g2[t] = a2;
    }
    __syncthreads();

    if (tid < 64) {
        float z  = sigmoidf_(g1[tid]       + g2[tid]);
        float r  = sigmoidf_(g1[64 + tid]  + g2[64 + tid]);
        float hh = tanhf_   (g1[128 + tid] + r * g2[128 + tid]);
        out[row * 64 + tid] = z * h1s[tid] + (1.f - z) * hh;
    }
}

extern "C" void kernel_launch(void* const* d_in, const int* in_sizes, int n_in,
                              void* d_out, int out_size, void* d_ws, size_t ws_size,
                              hipStream_t stream) {
    const float* nodes = (const float*)d_in[0];
    const float* edges = (const float*)d_in[1];
    const float* mask  = (const float*)d_in[2];
    const float* W_e   = (const float*)d_in[3];
    const float* b_e   = (const float*)d_in[4];
    const float* gk    = (const float*)d_in[5];
    const float* gr    = (const float*)d_in[6];
    const float* gb    = (const float*)d_in[7];
    float* out = (float*)d_out;

    _Float16* WT = (_Float16*)d_ws;            // 4096*32*2 = 256 KB

    prep_kernel<<<64, 256, 0, stream>>>(W_e, WT);
    fused_kernel<<<512, 512, 0, stream>>>(WT, edges, nodes, mask, b_e, gk, gr, gb, out);
}